// Round 12
// baseline (276.047 us; speedup 1.0000x reference)
//
#include <hip/hip_runtime.h>
#include <hip/hip_fp16.h>
#include <cstdint>
#include <cstddef>

#define N_NODES 50000
#define N_EDGES 1600000
#define NEG_SLOPE 0.2f
#define GAT_EPS 1e-16f

#define NCHUNK 128
#define CE (N_EDGES / NCHUNK)   // 12500
#define NBKT 196                 // ceil(50000/256)
#define GEMM_BLOCKS 782          // ceil(50000/64)

typedef _Float16 half8v __attribute__((ext_vector_type(8)));
typedef _Float16 half4v __attribute__((ext_vector_type(4)));
typedef float f32x4 __attribute__((ext_vector_type(4)));

// Channel permutation for h1 storage (MFMA C-reg native order):
// real c = ct*16 + m  <->  cperm = m*8 + ct

// ---------------- fused: MFMA GEMM blocks + histogram blocks + W2-prep block ----------------

__global__ __launch_bounds__(256) void k_gh(
    const float* __restrict__ x, const float* __restrict__ W1,
    const float* __restrict__ W2, const float* __restrict__ b1,
    const float* __restrict__ att_src, const float* __restrict__ att_dst,
    _Float16* __restrict__ h1p, float* __restrict__ a_src, float* __restrict__ a_dst,
    const int* __restrict__ ei, int* __restrict__ coarse,
    float* __restrict__ w2tp, float* __restrict__ b1p) {
    __shared__ __align__(16) char smem[34816];
    int t = threadIdx.x;
    int b = blockIdx.x;
    if (b == GEMM_BLOCKS + NCHUNK) {
        for (int i = t; i < 2112; i += 256) {   // 16 x 132
            int j = i / 132, kp = i % 132;
            float v = 0.f;
            if (kp < 128) {
                int real = (kp & 7) * 16 + (kp >> 3);
                v = W2[real * 16 + j];
            }
            w2tp[i] = v;
        }
        if (t < 128) {
            int real = (t & 7) * 16 + (t >> 3);
            b1p[t] = b1[real];
        }
        return;
    }
    if (b >= GEMM_BLOCKS) {
        // per-wave privatized histograms (4 x 256 bins); R24: int4 dst reads
        int* h = (int*)smem;   // 4 * 256 ints = 4KB
        int g = b - GEMM_BLOCKS;
        int wv = t >> 6;
        for (int i = t; i < 1024; i += 256) h[i] = 0;
        __syncthreads();
        int* hw = h + (wv << 8);
        const int4* d4 = (const int4*)(ei + N_EDGES + g * CE);   // 16B-aligned: CE*4=50000B %16==0
        for (int i = t; i < CE / 4; i += 256) {
            int4 v = d4[i];
            atomicAdd(&hw[v.x >> 8], 1);
            atomicAdd(&hw[v.y >> 8], 1);
            atomicAdd(&hw[v.z >> 8], 1);
            atomicAdd(&hw[v.w >> 8], 1);
        }
        __syncthreads();
        if (t < NBKT) coarse[g * NBKT + t] = h[t] + h[256 + t] + h[512 + t] + h[768 + t];
        return;
    }
    _Float16* wl = (_Float16*)smem;      // [128][136]
    for (int j = t; j < 16384; j += 256) {
        int k = j >> 7, c = j & 127;
        wl[c * 136 + k] = (_Float16)W1[j];
    }
    __syncthreads();
    int wv = t >> 6, lane = t & 63;
    int m = lane & 15, q = lane >> 4;
    int nb = b * 64 + wv * 16;
    int grow = nb + m;
    const float* xrow = x + (size_t)((grow < N_NODES) ? grow : (N_NODES - 1)) * 128;
    f32x4 acc[8];
#pragma unroll
    for (int ct = 0; ct < 8; ++ct) acc[ct] = (f32x4){0.f, 0.f, 0.f, 0.f};
#pragma unroll
    for (int kc = 0; kc < 4; ++kc) {
        float4 u0 = *(const float4*)(xrow + kc * 32 + q * 8);
        float4 u1 = *(const float4*)(xrow + kc * 32 + q * 8 + 4);
        half8v a;
        a[0] = (_Float16)u0.x; a[1] = (_Float16)u0.y;
        a[2] = (_Float16)u0.z; a[3] = (_Float16)u0.w;
        a[4] = (_Float16)u1.x; a[5] = (_Float16)u1.y;
        a[6] = (_Float16)u1.z; a[7] = (_Float16)u1.w;
#pragma unroll
        for (int ct = 0; ct < 8; ++ct) {
            half8v bf = *(const half8v*)(wl + (ct * 16 + m) * 136 + kc * 32 + q * 8);
            acc[ct] = __builtin_amdgcn_mfma_f32_16x16x32_f16(a, bf, acc[ct], 0, 0, 0);
        }
    }
    float att_s[8], att_d[8];
#pragma unroll
    for (int ct = 0; ct < 8; ++ct) {
        att_s[ct] = att_src[ct * 16 + m];
        att_d[ct] = att_dst[ct * 16 + m];
    }
#pragma unroll
    for (int r = 0; r < 4; ++r) {
        int gn = nb + q * 4 + r;
        half8v hv;
        float ps0 = 0.f, ps1 = 0.f, pd0 = 0.f, pd1 = 0.f;
#pragma unroll
        for (int ct = 0; ct < 8; ++ct) {
            float v = acc[ct][r];
            hv[ct] = (_Float16)v;
            if (ct < 4) { ps0 += v * att_s[ct]; pd0 += v * att_d[ct]; }
            else        { ps1 += v * att_s[ct]; pd1 += v * att_d[ct]; }
        }
#pragma unroll
        for (int off = 8; off >= 1; off >>= 1) {
            ps0 += __shfl_xor(ps0, off, 64);
            ps1 += __shfl_xor(ps1, off, 64);
            pd0 += __shfl_xor(pd0, off, 64);
            pd1 += __shfl_xor(pd1, off, 64);
        }
        if (gn < N_NODES) {
            *(half8v*)(h1p + (size_t)gn * 128 + m * 8) = hv;
            if (m == 0) {
                a_src[gn * 2 + 0] = ps0;
                a_src[gn * 2 + 1] = ps1;
                a_dst[gn * 2 + 0] = pd0;
                a_dst[gn * 2 + 1] = pd1;
            }
        }
    }
}

// ---------------- CSR build ----------------
// R24: no 100KB LDS staging — two direct coalesced passes over coarse
// (second pass L2-hot). 256 threads, one block.

__global__ __launch_bounds__(256) void k_cscan(const int* __restrict__ coarse,
                                               int* __restrict__ cbase,
                                               int* __restrict__ bb,
                                               int* __restrict__ row_start) {
    __shared__ int wt4[4];
    int t = threadIdx.x;
    int s = 0;
    if (t < NBKT)
        for (int g = 0; g < NCHUNK; ++g) s += coarse[g * NBKT + t];   // coalesced across t
    int lane = t & 63, w = t >> 6;
    int x = s;
#pragma unroll
    for (int off = 1; off < 64; off <<= 1) {
        int y = __shfl_up(x, off, 64);
        if (lane >= off) x += y;
    }
    if (lane == 63) wt4[w] = x;
    __syncthreads();
    int woff = 0;
    for (int i = 0; i < w; ++i) woff += wt4[i];
    if (t < NBKT) {
        int run = woff + x - s;
        bb[t] = run;
        for (int g = 0; g < NCHUNK; ++g) {
            cbase[g * NBKT + t] = run;     // coalesced across t
            run += coarse[g * NBKT + t];   // L2-hot re-read
        }
    }
    if (t == 0) { bb[NBKT] = N_EDGES; row_start[N_NODES] = N_EDGES; }
}

// R24: grid-stride over all edges, slot from global atomics on cbase
// (L2-resident 25088 counters, ~64 increments each) — uses all 256 CUs
// instead of 128 blocks at 0.5 waves/SIMD. part packed u32 (d<<16|s).

__global__ __launch_bounds__(256) void k_partition(const int* __restrict__ ei,
                                                   int* __restrict__ cbase,
                                                   unsigned int* __restrict__ part) {
    int tid = blockIdx.x * 256 + threadIdx.x;
    int stride = gridDim.x * 256;
    for (int e = tid; e < N_EDGES; e += stride) {
        int s = ei[e], d = ei[N_EDGES + e];
        int g = e / CE;                     // magic-mul division
        int slot = atomicAdd(&cbase[g * NBKT + (d >> 8)], 1);
        part[slot] = ((unsigned int)d << 16) | (unsigned int)s;
    }
}

// emits split csrc (4B src) + cw (8B float2 weights)
// R24: 512 threads/block (8 waves — latency hiding); scan logic on t<256.

__global__ __launch_bounds__(512) void k_local(const unsigned int* __restrict__ part,
                                               const int* __restrict__ bb,
                                               const float* __restrict__ a_src1,
                                               const float* __restrict__ a_dst1,
                                               int* __restrict__ row_start,
                                               int* __restrict__ csrc,
                                               float2* __restrict__ cw) {
    __shared__ int hist[256];
    __shared__ int fillv[256];
    __shared__ float2 adl[256];
    __shared__ int wtot[4];
    int t = threadIdx.x, b = blockIdx.x;
    int n0 = b << 8;
    int es = bb[b], ee = bb[b + 1];
    if (t < 256) {
        hist[t] = 0;
        if (n0 + t < N_NODES) adl[t] = ((const float2*)a_dst1)[n0 + t];
    }
    __syncthreads();
    for (int e = es + t; e < ee; e += 512) atomicAdd(&hist[(part[e] >> 16) - n0], 1);
    __syncthreads();
    int v = 0, x = 0, w = 0;
    if (t < 256) {
        int lane = t & 63; w = t >> 6;
        v = hist[t]; x = v;
#pragma unroll
        for (int off = 1; off < 64; off <<= 1) {
            int y = __shfl_up(x, off, 64);
            if (lane >= off) x += y;
        }
        if (lane == 63) wtot[w] = x;
    }
    __syncthreads();
    if (t < 256) {
        int woff = 0;
        for (int i = 0; i < w; ++i) woff += wtot[i];
        int excl = woff + x - v;
        if (n0 + t < N_NODES) row_start[n0 + t] = es + excl;
        fillv[t] = excl;
    }
    __syncthreads();
    for (int e = es + t; e < ee; e += 512) {
        unsigned int sd = part[e];
        int s = (int)(sd & 0xFFFFu);
        int j = (int)(sd >> 16) - n0;
        int slot = es + atomicAdd(&fillv[j], 1);
        float2 as = ((const float2*)a_src1)[s];
        float2 ad = adl[j];
        float e0 = as.x + ad.x; e0 = (e0 >= 0.f) ? e0 : NEG_SLOPE * e0;
        float e1 = as.y + ad.y; e1 = (e1 >= 0.f) ? e1 : NEG_SLOPE * e1;
        csrc[slot] = s;
        cw[slot] = make_float2(expf(e0), expf(e1));
    }
}

// ---------------- Layer 1 aggregation + ELU + fused layer-2 GEMM ----------------
// 16 lanes per edge (4 edges/wave-step), 16B half8v gathers, edge metadata
// staged in LDS; (src,w0,w1) broadcast via ds_read_b128 per 4 edges.
// Epilogue: per-(m16,qt) 2-channel ownership -> 2 expm1/lane.
// NOTE (R10 lesson): do NOT deepen the software pipeline here — +20 VGPR
// dropped occupancy 62->34% and cost +22 µs. TLP is the latency hider.

__global__ __launch_bounds__(256) void k_agg1f(
    const int* __restrict__ row_start, const int* __restrict__ csrc,
    const float2* __restrict__ cw,
    const _Float16* __restrict__ h1p, const float* __restrict__ b1p,
    const float* __restrict__ w2tp,
    const float* __restrict__ att_src2, const float* __restrict__ att_dst2,
    float* __restrict__ h2, float* __restrict__ as2, float* __restrict__ ad2) {
    __shared__ float w2l[16 * 132];
    __shared__ float rows[4][128];
    __shared__ int4 elds[4][64];
    int t = threadIdx.x;
    for (int i = t; i < 528; i += 256) ((float4*)w2l)[i] = ((const float4*)w2tp)[i];
    __syncthreads();
    int wv = t >> 6, lane = t & 63;
    int d = blockIdx.x * 4 + wv;
    int row = row_start[d], end = row_start[d + 1];
    int m16 = lane & 15;       // channel group: permuted channels [m16*8, m16*8+8)
    int qt = lane >> 4;        // edge slot within group of 4
    uint32_t moff = (uint32_t)m16 * 16u;   // byte offset into h1p row (8 halves)
    const char* hbase = (const char*)h1p;
    float den0 = 0.f, den1 = 0.f;
    float acc[8];
#pragma unroll
    for (int i = 0; i < 8; ++i) acc[i] = 0.f;
    for (int base = row; base < end; base += 64) {
        int m = end - base;
        if (m > 64) m = 64;
        // stage up to 64 edges into LDS (coalesced csrc+cw reads + 1 ds_write)
        int idx = base + lane;
        int idxc = (idx < end) ? idx : (end - 1);
        int s = csrc[idxc];
        float2 wv2 = cw[idxc];
        if (idx >= end) { wv2.x = 0.f; wv2.y = 0.f; }   // zero weights for padding
        elds[wv][lane] = make_int4(s, __float_as_int(wv2.x), __float_as_int(wv2.y), 0);
        int nc = (m + 3) >> 2;   // 4-edge steps
        auto step = [&](int p) {
            int4 md = elds[wv][p * 4 + qt];        // broadcast within 16-lane group
            float w0 = __int_as_float(md.y);
            float w1 = __int_as_float(md.z);
            uint32_t off = ((uint32_t)md.x << 8) + moff;
            half8v hv = *(const half8v*)(hbase + off);
            den0 += w0;
            den1 += w1;
            acc[0] += w0 * (float)hv[0];
            acc[1] += w0 * (float)hv[1];
            acc[2] += w0 * (float)hv[2];
            acc[3] += w0 * (float)hv[3];
            acc[4] += w1 * (float)hv[4];
            acc[5] += w1 * (float)hv[5];
            acc[6] += w1 * (float)hv[6];
            acc[7] += w1 * (float)hv[7];
        };
        int p = 0;
        for (; p + 4 <= nc; p += 4) {
            step(p); step(p + 1); step(p + 2); step(p + 3);
        }
        for (; p < nc; ++p) step(p);
    }
    // reduce across the 4 edge-groups (quarters) -> all lanes hold full sums
#pragma unroll
    for (int i = 0; i < 8; ++i) {
        acc[i] += __shfl_xor(acc[i], 16, 64);
        acc[i] += __shfl_xor(acc[i], 32, 64);
    }
    den0 += __shfl_xor(den0, 16, 64);
    den0 += __shfl_xor(den0, 32, 64);
    den1 += __shfl_xor(den1, 16, 64);
    den1 += __shfl_xor(den1, 32, 64);
    float inv0 = 1.f / (den0 + GAT_EPS);
    float inv1 = 1.f / (den1 + GAT_EPS);
    // lane (m16,qt) owns 2 channels cperm = m16*8 + qt*2 + {0,1}
    {
        int cbase2 = qt * 2;                  // 0,2,4,6
        float inv = (cbase2 < 4) ? inv0 : inv1;
        float2 bv = *(const float2*)(b1p + m16 * 8 + cbase2);
        float oa = acc[cbase2] * inv + bv.x;
        float ob = acc[cbase2 + 1] * inv + bv.y;
        oa = (oa > 0.f) ? oa : expm1f(oa);
        ob = (ob > 0.f) ? ob : expm1f(ob);
        *(float2*)(&rows[wv][m16 * 8 + cbase2]) = make_float2(oa, ob);
    }
    // fused gemm2, q-rotated phases
    int j = lane & 15, q = lane >> 4;
    const float* r = rows[wv];
    const float* wt = &w2l[j * 132];
    int k0 = q * 32;
    float acc2 = 0.f;
#pragma unroll
    for (int sI = 0; sI < 8; ++sI) {
        int sp = ((sI + q) & 7) * 4;
        float4 rv = *(const float4*)(r + k0 + sp);
        float4 w4 = *(const float4*)(wt + k0 + sp);
        acc2 += rv.x * w4.x + rv.y * w4.y + rv.z * w4.z + rv.w * w4.w;
    }
    acc2 += __shfl_xor(acc2, 16, 64);
    acc2 += __shfl_xor(acc2, 32, 64);
    if (lane < 16) {
        h2[(size_t)d * 16 + j] = acc2;
        float ps = acc2 * att_src2[j];
        float pd = acc2 * att_dst2[j];
#pragma unroll
        for (int off = 8; off >= 1; off >>= 1) {
            ps += __shfl_xor(ps, off, 64);
            pd += __shfl_xor(pd, off, 64);
        }
        if (lane == 0) { as2[d] = ps; ad2[d] = pd; }
    }
}

// ---------------- Layer 2 aggregation + bias + softmax ----------------
// 4 lanes per edge (16 edges/wave-step), float4 h2 loads.

__global__ __launch_bounds__(256) void k_agg2(
    const int* __restrict__ row_start, const int* __restrict__ csrc,
    const float* __restrict__ h2, const float* __restrict__ as2,
    const float* __restrict__ ad2, const float* __restrict__ b2,
    float* __restrict__ out) {
    __shared__ int2 elds[4][64];
    int t = threadIdx.x;
    int wv = t >> 6, lane = t & 63;
    int d = blockIdx.x * 4 + wv;
    int row = row_start[d], end = row_start[d + 1];
    float ad = ad2[d];
    int g16 = lane >> 2;      // edge slot within group of 16
    int cq = lane & 3;        // channel quad: channels cq*4..cq*4+3
    float den = 0.f;
    float ax = 0.f, ay = 0.f, az = 0.f, aw = 0.f;
    for (int base = row; base < end; base += 64) {
        int m = end - base;
        if (m > 64) m = 64;
        int idx = base + lane;
        int idxc = (idx < end) ? idx : (end - 1);
        int s = csrc[idxc];
        float w = 0.f;
        if (idx < end) {
            float e = as2[s] + ad;
            e = (e >= 0.f) ? e : NEG_SLOPE * e;
            w = expf(e);
        }
        den += w;
        elds[wv][lane] = make_int2(s, __float_as_int(w));
        int nc = (m + 15) >> 4;   // 16-edge steps
        auto step = [&](int p) {
            int2 md = elds[wv][p * 16 + g16];   // broadcast within 4-lane group
            float wj = __int_as_float(md.y);
            float4 hv = *(const float4*)(h2 + (size_t)md.x * 16 + cq * 4);
            ax += wj * hv.x;
            ay += wj * hv.y;
            az += wj * hv.z;
            aw += wj * hv.w;
        };
        int p = 0;
        for (; p + 4 <= nc; p += 4) {
            step(p); step(p + 1); step(p + 2); step(p + 3);
        }
        for (; p < nc; ++p) step(p);
    }
    // den: full 64-lane sum (each lane staged one edge)
#pragma unroll
    for (int off = 32; off >= 1; off >>= 1) den += __shfl_xor(den, off, 64);
    // acc: reduce across edge groups (lane bits 2..5)
#pragma unroll
    for (int off = 4; off <= 32; off <<= 1) {
        ax += __shfl_xor(ax, off, 64);
        ay += __shfl_xor(ay, off, 64);
        az += __shfl_xor(az, off, 64);
        aw += __shfl_xor(aw, off, 64);
    }
    float inv = 1.f / (den + GAT_EPS);
    const float4 b4 = *(const float4*)(b2 + cq * 4);
    float v0 = ax * inv + b4.x;
    float v1 = ay * inv + b4.y;
    float v2 = az * inv + b4.z;
    float v3 = aw * inv + b4.w;
    // softmax over 16 channels spread across the 4 cq values (lane bits 0..1)
    float mmax = fmaxf(fmaxf(v0, v1), fmaxf(v2, v3));
    mmax = fmaxf(mmax, __shfl_xor(mmax, 1, 64));
    mmax = fmaxf(mmax, __shfl_xor(mmax, 2, 64));
    float e0 = expf(v0 - mmax);
    float e1 = expf(v1 - mmax);
    float e2 = expf(v2 - mmax);
    float e3 = expf(v3 - mmax);
    float sum = e0 + e1 + e2 + e3;
    sum += __shfl_xor(sum, 1, 64);
    sum += __shfl_xor(sum, 2, 64);
    float isum = 1.f / sum;
    if (g16 == 0)
        *(float4*)(out + (size_t)d * 16 + cq * 4) =
            make_float4(e0 * isum, e1 * isum, e2 * isum, e3 * isum);
}

// ---------------- launch ----------------

extern "C" void kernel_launch(void* const* d_in, const int* in_sizes, int n_in,
                              void* d_out, int out_size, void* d_ws, size_t ws_size,
                              hipStream_t stream) {
    const float* x        = (const float*)d_in[0];
    const float* W1       = (const float*)d_in[1];
    const float* att_src1 = (const float*)d_in[2];
    const float* att_dst1 = (const float*)d_in[3];
    const float* b1       = (const float*)d_in[4];
    const float* W2       = (const float*)d_in[5];
    const float* att_src2 = (const float*)d_in[6];
    const float* att_dst2 = (const float*)d_in[7];
    const float* b2       = (const float*)d_in[8];
    const int*   ei       = (const int*)d_in[9];   // [2, E]: src row then dst row

    char* p = (char*)d_ws;
    auto alloc = [&](size_t bytes) {
        char* r = p;
        p += (bytes + 255) & ~(size_t)255;
        return r;
    };
    _Float16* h1p  = (_Float16*)alloc(sizeof(_Float16) * (size_t)N_NODES * 128);
    float* w2tp    = (float*)alloc(sizeof(float) * 16 * 132);
    float* b1p     = (float*)alloc(sizeof(float) * 128);
    float* h2      = (float*)alloc(sizeof(float) * (size_t)N_NODES * 16);
    float* a_src   = (float*)alloc(sizeof(float) * N_NODES * 2);
    float* a_dst   = (float*)alloc(sizeof(float) * N_NODES * 2);
    float* as2     = (float*)alloc(sizeof(float) * N_NODES);
    float* ad2     = (float*)alloc(sizeof(float) * N_NODES);
    int* coarse    = (int*)alloc(sizeof(int) * NBKT * NCHUNK);
    int* cbase     = (int*)alloc(sizeof(int) * NBKT * NCHUNK);
    int* bb        = (int*)alloc(sizeof(int) * (NBKT + 1));
    int* row_start = (int*)alloc(sizeof(int) * (N_NODES + 1));
    unsigned int* part = (unsigned int*)alloc(sizeof(unsigned int) * (size_t)N_EDGES);
    int* csrc      = (int*)alloc(sizeof(int) * (size_t)N_EDGES);
    float2* cw     = (float2*)alloc(sizeof(float2) * (size_t)N_EDGES);

    k_gh<<<GEMM_BLOCKS + NCHUNK + 1, 256, 0, stream>>>(x, W1, W2, b1, att_src1, att_dst1,
                                                       h1p, a_src, a_dst, ei, coarse, w2tp, b1p);
    k_cscan<<<1, 256, 0, stream>>>(coarse, cbase, bb, row_start);
    k_partition<<<2048, 256, 0, stream>>>(ei, cbase, part);
    k_local<<<NBKT, 512, 0, stream>>>(part, bb, a_src, a_dst, row_start, csrc, cw);
    k_agg1f<<<N_NODES / 4, 256, 0, stream>>>(row_start, csrc, cw, h1p, b1p, w2tp, att_src2, att_dst2, h2, as2, ad2);
    k_agg2<<<N_NODES / 4, 256, 0, stream>>>(row_start, csrc, h2, as2, ad2, b2, (float*)d_out);
}

// Round 13
// 232.368 us; speedup vs baseline: 1.1880x; 1.1880x over previous
//
#include <hip/hip_runtime.h>
#include <hip/hip_fp16.h>
#include <cstdint>
#include <cstddef>

#define N_NODES 50000
#define N_EDGES 1600000
#define NEG_SLOPE 0.2f
#define GAT_EPS 1e-16f

#define NCHUNK 128
#define CE (N_EDGES / NCHUNK)   // 12500
#define NBKT 196                 // ceil(50000/256)
#define GEMM_BLOCKS 782          // ceil(50000/64)

typedef _Float16 half8v __attribute__((ext_vector_type(8)));
typedef _Float16 half4v __attribute__((ext_vector_type(4)));
typedef float f32x4 __attribute__((ext_vector_type(4)));

// Channel permutation for h1 storage (MFMA C-reg native order):
// real c = ct*16 + m  <->  cperm = m*8 + ct

// ---------------- fused: MFMA GEMM blocks + histogram blocks + W2-prep block ----------------

__global__ __launch_bounds__(256) void k_gh(
    const float* __restrict__ x, const float* __restrict__ W1,
    const float* __restrict__ W2, const float* __restrict__ b1,
    const float* __restrict__ att_src, const float* __restrict__ att_dst,
    _Float16* __restrict__ h1p, float* __restrict__ a_src, float* __restrict__ a_dst,
    const int* __restrict__ ei, int* __restrict__ coarse,
    float* __restrict__ w2tp, float* __restrict__ b1p) {
    __shared__ __align__(16) char smem[34816];
    int t = threadIdx.x;
    int b = blockIdx.x;
    if (b == GEMM_BLOCKS + NCHUNK) {
        for (int i = t; i < 2112; i += 256) {   // 16 x 132
            int j = i / 132, kp = i % 132;
            float v = 0.f;
            if (kp < 128) {
                int real = (kp & 7) * 16 + (kp >> 3);
                v = W2[real * 16 + j];
            }
            w2tp[i] = v;
        }
        if (t < 128) {
            int real = (t & 7) * 16 + (t >> 3);
            b1p[t] = b1[real];
        }
        return;
    }
    if (b >= GEMM_BLOCKS) {
        // per-wave privatized histograms (4 x 256 bins); int4 dst reads
        int* h = (int*)smem;   // 4 * 256 ints = 4KB
        int g = b - GEMM_BLOCKS;
        int wv = t >> 6;
        for (int i = t; i < 1024; i += 256) h[i] = 0;
        __syncthreads();
        int* hw = h + (wv << 8);
        const int4* d4 = (const int4*)(ei + N_EDGES + g * CE);   // 16B-aligned: CE*4=50000B %16==0
        for (int i = t; i < CE / 4; i += 256) {
            int4 v = d4[i];
            atomicAdd(&hw[v.x >> 8], 1);
            atomicAdd(&hw[v.y >> 8], 1);
            atomicAdd(&hw[v.z >> 8], 1);
            atomicAdd(&hw[v.w >> 8], 1);
        }
        __syncthreads();
        if (t < NBKT) coarse[g * NBKT + t] = h[t] + h[256 + t] + h[512 + t] + h[768 + t];
        return;
    }
    _Float16* wl = (_Float16*)smem;      // [128][136]
    for (int j = t; j < 16384; j += 256) {
        int k = j >> 7, c = j & 127;
        wl[c * 136 + k] = (_Float16)W1[j];
    }
    __syncthreads();
    int wv = t >> 6, lane = t & 63;
    int m = lane & 15, q = lane >> 4;
    int nb = b * 64 + wv * 16;
    int grow = nb + m;
    const float* xrow = x + (size_t)((grow < N_NODES) ? grow : (N_NODES - 1)) * 128;
    f32x4 acc[8];
#pragma unroll
    for (int ct = 0; ct < 8; ++ct) acc[ct] = (f32x4){0.f, 0.f, 0.f, 0.f};
#pragma unroll
    for (int kc = 0; kc < 4; ++kc) {
        float4 u0 = *(const float4*)(xrow + kc * 32 + q * 8);
        float4 u1 = *(const float4*)(xrow + kc * 32 + q * 8 + 4);
        half8v a;
        a[0] = (_Float16)u0.x; a[1] = (_Float16)u0.y;
        a[2] = (_Float16)u0.z; a[3] = (_Float16)u0.w;
        a[4] = (_Float16)u1.x; a[5] = (_Float16)u1.y;
        a[6] = (_Float16)u1.z; a[7] = (_Float16)u1.w;
#pragma unroll
        for (int ct = 0; ct < 8; ++ct) {
            half8v bf = *(const half8v*)(wl + (ct * 16 + m) * 136 + kc * 32 + q * 8);
            acc[ct] = __builtin_amdgcn_mfma_f32_16x16x32_f16(a, bf, acc[ct], 0, 0, 0);
        }
    }
    float att_s[8], att_d[8];
#pragma unroll
    for (int ct = 0; ct < 8; ++ct) {
        att_s[ct] = att_src[ct * 16 + m];
        att_d[ct] = att_dst[ct * 16 + m];
    }
#pragma unroll
    for (int r = 0; r < 4; ++r) {
        int gn = nb + q * 4 + r;
        half8v hv;
        float ps0 = 0.f, ps1 = 0.f, pd0 = 0.f, pd1 = 0.f;
#pragma unroll
        for (int ct = 0; ct < 8; ++ct) {
            float v = acc[ct][r];
            hv[ct] = (_Float16)v;
            if (ct < 4) { ps0 += v * att_s[ct]; pd0 += v * att_d[ct]; }
            else        { ps1 += v * att_s[ct]; pd1 += v * att_d[ct]; }
        }
#pragma unroll
        for (int off = 8; off >= 1; off >>= 1) {
            ps0 += __shfl_xor(ps0, off, 64);
            ps1 += __shfl_xor(ps1, off, 64);
            pd0 += __shfl_xor(pd0, off, 64);
            pd1 += __shfl_xor(pd1, off, 64);
        }
        if (gn < N_NODES) {
            *(half8v*)(h1p + (size_t)gn * 128 + m * 8) = hv;
            if (m == 0) {
                a_src[gn * 2 + 0] = ps0;
                a_src[gn * 2 + 1] = ps1;
                a_dst[gn * 2 + 0] = pd0;
                a_dst[gn * 2 + 1] = pd1;
            }
        }
    }
}

// ---------------- CSR build ----------------
// no LDS staging — two direct coalesced passes over coarse (2nd L2-hot).

__global__ __launch_bounds__(256) void k_cscan(const int* __restrict__ coarse,
                                               int* __restrict__ cbase,
                                               int* __restrict__ bb,
                                               int* __restrict__ row_start) {
    __shared__ int wt4[4];
    int t = threadIdx.x;
    int s = 0;
    if (t < NBKT)
        for (int g = 0; g < NCHUNK; ++g) s += coarse[g * NBKT + t];   // coalesced across t
    int lane = t & 63, w = t >> 6;
    int x = s;
#pragma unroll
    for (int off = 1; off < 64; off <<= 1) {
        int y = __shfl_up(x, off, 64);
        if (lane >= off) x += y;
    }
    if (lane == 63) wt4[w] = x;
    __syncthreads();
    int woff = 0;
    for (int i = 0; i < w; ++i) woff += wt4[i];
    if (t < NBKT) {
        int run = woff + x - s;
        bb[t] = run;
        for (int g = 0; g < NCHUNK; ++g) {
            cbase[g * NBKT + t] = run;     // coalesced across t
            run += coarse[g * NBKT + t];   // L2-hot re-read
        }
    }
    if (t == 0) { bb[NBKT] = N_EDGES; row_start[N_NODES] = N_EDGES; }
}

// R25: back to chunked-LDS slot allocation (bucket-local scatter => full-line
// writes, 13MB not 53MB — R12's global-atomic version was store-RMW-bound),
// but 1024 threads/block: 16 waves vs 4 => 4x latency hiding, same traffic.

__global__ __launch_bounds__(1024) void k_partition(const int* __restrict__ ei,
                                                    const int* __restrict__ cbase,
                                                    unsigned int* __restrict__ part) {
    __shared__ int loc[NBKT];
    int t = threadIdx.x, g = blockIdx.x;
    if (t < NBKT) loc[t] = cbase[g * NBKT + t];   // coalesced
    __syncthreads();
    int e0 = g * CE;
    for (int e = e0 + t; e < e0 + CE; e += 1024) {
        int s = ei[e], d = ei[N_EDGES + e];
        int slot = atomicAdd(&loc[d >> 8], 1);
        part[slot] = ((unsigned int)d << 16) | (unsigned int)s;
    }
}

// emits split csrc (4B src) + cw (8B float2 weights)
// 512 threads/block (8 waves — latency hiding); scan logic on t<256.

__global__ __launch_bounds__(512) void k_local(const unsigned int* __restrict__ part,
                                               const int* __restrict__ bb,
                                               const float* __restrict__ a_src1,
                                               const float* __restrict__ a_dst1,
                                               int* __restrict__ row_start,
                                               int* __restrict__ csrc,
                                               float2* __restrict__ cw) {
    __shared__ int hist[256];
    __shared__ int fillv[256];
    __shared__ float2 adl[256];
    __shared__ int wtot[4];
    int t = threadIdx.x, b = blockIdx.x;
    int n0 = b << 8;
    int es = bb[b], ee = bb[b + 1];
    if (t < 256) {
        hist[t] = 0;
        if (n0 + t < N_NODES) adl[t] = ((const float2*)a_dst1)[n0 + t];
    }
    __syncthreads();
    for (int e = es + t; e < ee; e += 512) atomicAdd(&hist[(part[e] >> 16) - n0], 1);
    __syncthreads();
    int v = 0, x = 0, w = 0;
    if (t < 256) {
        int lane = t & 63; w = t >> 6;
        v = hist[t]; x = v;
#pragma unroll
        for (int off = 1; off < 64; off <<= 1) {
            int y = __shfl_up(x, off, 64);
            if (lane >= off) x += y;
        }
        if (lane == 63) wtot[w] = x;
    }
    __syncthreads();
    if (t < 256) {
        int woff = 0;
        for (int i = 0; i < w; ++i) woff += wtot[i];
        int excl = woff + x - v;
        if (n0 + t < N_NODES) row_start[n0 + t] = es + excl;
        fillv[t] = excl;
    }
    __syncthreads();
    for (int e = es + t; e < ee; e += 512) {
        unsigned int sd = part[e];
        int s = (int)(sd & 0xFFFFu);
        int j = (int)(sd >> 16) - n0;
        int slot = es + atomicAdd(&fillv[j], 1);
        float2 as = ((const float2*)a_src1)[s];
        float2 ad = adl[j];
        float e0 = as.x + ad.x; e0 = (e0 >= 0.f) ? e0 : NEG_SLOPE * e0;
        float e1 = as.y + ad.y; e1 = (e1 >= 0.f) ? e1 : NEG_SLOPE * e1;
        csrc[slot] = s;
        cw[slot] = make_float2(expf(e0), expf(e1));
    }
}

// ---------------- Layer 1 aggregation + ELU + fused layer-2 GEMM ----------------
// 16 lanes per edge (4 edges/wave-step), 16B half8v gathers, edge metadata
// staged in LDS; (src,w0,w1) broadcast via ds_read_b128 per 4 edges.
// Epilogue: per-(m16,qt) 2-channel ownership -> 2 expm1/lane.
// NOTE (R10 lesson): do NOT deepen the software pipeline here — +20 VGPR
// dropped occupancy 62->34% and cost +22 µs. TLP is the latency hider.

__global__ __launch_bounds__(256) void k_agg1f(
    const int* __restrict__ row_start, const int* __restrict__ csrc,
    const float2* __restrict__ cw,
    const _Float16* __restrict__ h1p, const float* __restrict__ b1p,
    const float* __restrict__ w2tp,
    const float* __restrict__ att_src2, const float* __restrict__ att_dst2,
    float* __restrict__ h2, float* __restrict__ as2, float* __restrict__ ad2) {
    __shared__ float w2l[16 * 132];
    __shared__ float rows[4][128];
    __shared__ int4 elds[4][64];
    int t = threadIdx.x;
    for (int i = t; i < 528; i += 256) ((float4*)w2l)[i] = ((const float4*)w2tp)[i];
    __syncthreads();
    int wv = t >> 6, lane = t & 63;
    int d = blockIdx.x * 4 + wv;
    int row = row_start[d], end = row_start[d + 1];
    int m16 = lane & 15;       // channel group: permuted channels [m16*8, m16*8+8)
    int qt = lane >> 4;        // edge slot within group of 4
    uint32_t moff = (uint32_t)m16 * 16u;   // byte offset into h1p row (8 halves)
    const char* hbase = (const char*)h1p;
    float den0 = 0.f, den1 = 0.f;
    float acc[8];
#pragma unroll
    for (int i = 0; i < 8; ++i) acc[i] = 0.f;
    for (int base = row; base < end; base += 64) {
        int m = end - base;
        if (m > 64) m = 64;
        // stage up to 64 edges into LDS (coalesced csrc+cw reads + 1 ds_write)
        int idx = base + lane;
        int idxc = (idx < end) ? idx : (end - 1);
        int s = csrc[idxc];
        float2 wv2 = cw[idxc];
        if (idx >= end) { wv2.x = 0.f; wv2.y = 0.f; }   // zero weights for padding
        elds[wv][lane] = make_int4(s, __float_as_int(wv2.x), __float_as_int(wv2.y), 0);
        int nc = (m + 3) >> 2;   // 4-edge steps
        auto step = [&](int p) {
            int4 md = elds[wv][p * 4 + qt];        // broadcast within 16-lane group
            float w0 = __int_as_float(md.y);
            float w1 = __int_as_float(md.z);
            uint32_t off = ((uint32_t)md.x << 8) + moff;
            half8v hv = *(const half8v*)(hbase + off);
            den0 += w0;
            den1 += w1;
            acc[0] += w0 * (float)hv[0];
            acc[1] += w0 * (float)hv[1];
            acc[2] += w0 * (float)hv[2];
            acc[3] += w0 * (float)hv[3];
            acc[4] += w1 * (float)hv[4];
            acc[5] += w1 * (float)hv[5];
            acc[6] += w1 * (float)hv[6];
            acc[7] += w1 * (float)hv[7];
        };
        int p = 0;
        for (; p + 4 <= nc; p += 4) {
            step(p); step(p + 1); step(p + 2); step(p + 3);
        }
        for (; p < nc; ++p) step(p);
    }
    // reduce across the 4 edge-groups (quarters) -> all lanes hold full sums
#pragma unroll
    for (int i = 0; i < 8; ++i) {
        acc[i] += __shfl_xor(acc[i], 16, 64);
        acc[i] += __shfl_xor(acc[i], 32, 64);
    }
    den0 += __shfl_xor(den0, 16, 64);
    den0 += __shfl_xor(den0, 32, 64);
    den1 += __shfl_xor(den1, 16, 64);
    den1 += __shfl_xor(den1, 32, 64);
    float inv0 = 1.f / (den0 + GAT_EPS);
    float inv1 = 1.f / (den1 + GAT_EPS);
    // lane (m16,qt) owns 2 channels cperm = m16*8 + qt*2 + {0,1}
    {
        int cbase2 = qt * 2;                  // 0,2,4,6
        float inv = (cbase2 < 4) ? inv0 : inv1;
        float2 bv = *(const float2*)(b1p + m16 * 8 + cbase2);
        float oa = acc[cbase2] * inv + bv.x;
        float ob = acc[cbase2 + 1] * inv + bv.y;
        oa = (oa > 0.f) ? oa : expm1f(oa);
        ob = (ob > 0.f) ? ob : expm1f(ob);
        *(float2*)(&rows[wv][m16 * 8 + cbase2]) = make_float2(oa, ob);
    }
    // fused gemm2, q-rotated phases
    int j = lane & 15, q = lane >> 4;
    const float* r = rows[wv];
    const float* wt = &w2l[j * 132];
    int k0 = q * 32;
    float acc2 = 0.f;
#pragma unroll
    for (int sI = 0; sI < 8; ++sI) {
        int sp = ((sI + q) & 7) * 4;
        float4 rv = *(const float4*)(r + k0 + sp);
        float4 w4 = *(const float4*)(wt + k0 + sp);
        acc2 += rv.x * w4.x + rv.y * w4.y + rv.z * w4.z + rv.w * w4.w;
    }
    acc2 += __shfl_xor(acc2, 16, 64);
    acc2 += __shfl_xor(acc2, 32, 64);
    if (lane < 16) {
        h2[(size_t)d * 16 + j] = acc2;
        float ps = acc2 * att_src2[j];
        float pd = acc2 * att_dst2[j];
#pragma unroll
        for (int off = 8; off >= 1; off >>= 1) {
            ps += __shfl_xor(ps, off, 64);
            pd += __shfl_xor(pd, off, 64);
        }
        if (lane == 0) { as2[d] = ps; ad2[d] = pd; }
    }
}

// ---------------- Layer 2 aggregation + bias + softmax ----------------
// 4 lanes per edge (16 edges/wave-step), float4 h2 loads.

__global__ __launch_bounds__(256) void k_agg2(
    const int* __restrict__ row_start, const int* __restrict__ csrc,
    const float* __restrict__ h2, const float* __restrict__ as2,
    const float* __restrict__ ad2, const float* __restrict__ b2,
    float* __restrict__ out) {
    __shared__ int2 elds[4][64];
    int t = threadIdx.x;
    int wv = t >> 6, lane = t & 63;
    int d = blockIdx.x * 4 + wv;
    int row = row_start[d], end = row_start[d + 1];
    float ad = ad2[d];
    int g16 = lane >> 2;      // edge slot within group of 16
    int cq = lane & 3;        // channel quad: channels cq*4..cq*4+3
    float den = 0.f;
    float ax = 0.f, ay = 0.f, az = 0.f, aw = 0.f;
    for (int base = row; base < end; base += 64) {
        int m = end - base;
        if (m > 64) m = 64;
        int idx = base + lane;
        int idxc = (idx < end) ? idx : (end - 1);
        int s = csrc[idxc];
        float w = 0.f;
        if (idx < end) {
            float e = as2[s] + ad;
            e = (e >= 0.f) ? e : NEG_SLOPE * e;
            w = expf(e);
        }
        den += w;
        elds[wv][lane] = make_int2(s, __float_as_int(w));
        int nc = (m + 15) >> 4;   // 16-edge steps
        auto step = [&](int p) {
            int2 md = elds[wv][p * 16 + g16];   // broadcast within 4-lane group
            float wj = __int_as_float(md.y);
            float4 hv = *(const float4*)(h2 + (size_t)md.x * 16 + cq * 4);
            ax += wj * hv.x;
            ay += wj * hv.y;
            az += wj * hv.z;
            aw += wj * hv.w;
        };
        int p = 0;
        for (; p + 4 <= nc; p += 4) {
            step(p); step(p + 1); step(p + 2); step(p + 3);
        }
        for (; p < nc; ++p) step(p);
    }
    // den: full 64-lane sum (each lane staged one edge)
#pragma unroll
    for (int off = 32; off >= 1; off >>= 1) den += __shfl_xor(den, off, 64);
    // acc: reduce across edge groups (lane bits 2..5)
#pragma unroll
    for (int off = 4; off <= 32; off <<= 1) {
        ax += __shfl_xor(ax, off, 64);
        ay += __shfl_xor(ay, off, 64);
        az += __shfl_xor(az, off, 64);
        aw += __shfl_xor(aw, off, 64);
    }
    float inv = 1.f / (den + GAT_EPS);
    const float4 b4 = *(const float4*)(b2 + cq * 4);
    float v0 = ax * inv + b4.x;
    float v1 = ay * inv + b4.y;
    float v2 = az * inv + b4.z;
    float v3 = aw * inv + b4.w;
    // softmax over 16 channels spread across the 4 cq values (lane bits 0..1)
    float mmax = fmaxf(fmaxf(v0, v1), fmaxf(v2, v3));
    mmax = fmaxf(mmax, __shfl_xor(mmax, 1, 64));
    mmax = fmaxf(mmax, __shfl_xor(mmax, 2, 64));
    float e0 = expf(v0 - mmax);
    float e1 = expf(v1 - mmax);
    float e2 = expf(v2 - mmax);
    float e3 = expf(v3 - mmax);
    float sum = e0 + e1 + e2 + e3;
    sum += __shfl_xor(sum, 1, 64);
    sum += __shfl_xor(sum, 2, 64);
    float isum = 1.f / sum;
    if (g16 == 0)
        *(float4*)(out + (size_t)d * 16 + cq * 4) =
            make_float4(e0 * isum, e1 * isum, e2 * isum, e3 * isum);
}

// ---------------- launch ----------------

extern "C" void kernel_launch(void* const* d_in, const int* in_sizes, int n_in,
                              void* d_out, int out_size, void* d_ws, size_t ws_size,
                              hipStream_t stream) {
    const float* x        = (const float*)d_in[0];
    const float* W1       = (const float*)d_in[1];
    const float* att_src1 = (const float*)d_in[2];
    const float* att_dst1 = (const float*)d_in[3];
    const float* b1       = (const float*)d_in[4];
    const float* W2       = (const float*)d_in[5];
    const float* att_src2 = (const float*)d_in[6];
    const float* att_dst2 = (const float*)d_in[7];
    const float* b2       = (const float*)d_in[8];
    const int*   ei       = (const int*)d_in[9];   // [2, E]: src row then dst row

    char* p = (char*)d_ws;
    auto alloc = [&](size_t bytes) {
        char* r = p;
        p += (bytes + 255) & ~(size_t)255;
        return r;
    };
    _Float16* h1p  = (_Float16*)alloc(sizeof(_Float16) * (size_t)N_NODES * 128);
    float* w2tp    = (float*)alloc(sizeof(float) * 16 * 132);
    float* b1p     = (float*)alloc(sizeof(float) * 128);
    float* h2      = (float*)alloc(sizeof(float) * (size_t)N_NODES * 16);
    float* a_src   = (float*)alloc(sizeof(float) * N_NODES * 2);
    float* a_dst   = (float*)alloc(sizeof(float) * N_NODES * 2);
    float* as2     = (float*)alloc(sizeof(float) * N_NODES);
    float* ad2     = (float*)alloc(sizeof(float) * N_NODES);
    int* coarse    = (int*)alloc(sizeof(int) * NBKT * NCHUNK);
    int* cbase     = (int*)alloc(sizeof(int) * NBKT * NCHUNK);
    int* bb        = (int*)alloc(sizeof(int) * (NBKT + 1));
    int* row_start = (int*)alloc(sizeof(int) * (N_NODES + 1));
    unsigned int* part = (unsigned int*)alloc(sizeof(unsigned int) * (size_t)N_EDGES);
    int* csrc      = (int*)alloc(sizeof(int) * (size_t)N_EDGES);
    float2* cw     = (float2*)alloc(sizeof(float2) * (size_t)N_EDGES);

    k_gh<<<GEMM_BLOCKS + NCHUNK + 1, 256, 0, stream>>>(x, W1, W2, b1, att_src1, att_dst1,
                                                       h1p, a_src, a_dst, ei, coarse, w2tp, b1p);
    k_cscan<<<1, 256, 0, stream>>>(coarse, cbase, bb, row_start);
    k_partition<<<NCHUNK, 1024, 0, stream>>>(ei, cbase, part);
    k_local<<<NBKT, 512, 0, stream>>>(part, bb, a_src, a_dst, row_start, csrc, cw);
    k_agg1f<<<N_NODES / 4, 256, 0, stream>>>(row_start, csrc, cw, h1p, b1p, w2tp, att_src2, att_dst2, h2, as2, ad2);
    k_agg2<<<N_NODES / 4, 256, 0, stream>>>(row_start, csrc, h2, as2, ad2, b2, (float*)d_out);
}